// Round 7
// baseline (438.557 us; speedup 1.0000x reference)
//
#include <hip/hip_runtime.h>

#define BINS 5
#define PTS  2
constexpr int Bx = 2, Cc = 256, Hh = 100, Ww = 152;
constexpr int HW = Hh * Ww;          // 15200
constexpr float EPS_DIV = 1e-6f;
constexpr float GN_EPS  = 1e-5f;

typedef __attribute__((ext_vector_type(8))) short bfrag;   // 8 bf16 (4 VGPRs)
typedef __attribute__((ext_vector_type(4))) float f32x4;   // MFMA C/D

__device__ __forceinline__ ushort f2bf(float f) {
    union { float f; unsigned u; } v; v.f = f;
    unsigned r = v.u + 0x7fffu + ((v.u >> 16) & 1u);
    return (ushort)(r >> 16);
}
__device__ __forceinline__ float bflo(unsigned u) {
    return __uint_as_float(u << 16);
}
__device__ __forceinline__ float bfhi(unsigned u) {
    return __uint_as_float(u & 0xffff0000u);
}
__device__ __forceinline__ unsigned pack2(float a, float b) {
    return (unsigned)f2bf(a) | ((unsigned)f2bf(b) << 16);
}

// ---------------------------------------------------------------------------
// K0: convert ef_w, hm1_w, merge_w to bf16 (each 131072 elems) + zero GN parts
// ---------------------------------------------------------------------------
__global__ __launch_bounds__(256)
void k_wconv(const float* __restrict__ efw, const float* __restrict__ w1,
             const float* __restrict__ mw, ushort* __restrict__ wb,
             float* __restrict__ part)
{
    if (blockIdx.x == 0 && threadIdx.x < 128) part[threadIdx.x] = 0.f;
    int gid = blockIdx.x * 256 + threadIdx.x;
    int e = gid * 4;
    int arr = e >> 17, off = e & 131071;
    const float* src = arr == 0 ? efw : (arr == 1 ? w1 : mw);
    float4 v = *(const float4*)(src + off);
    ushort4 o = { f2bf(v.x), f2bf(v.y), f2bf(v.z), f2bf(v.w) };
    *(ushort4*)(wb + e) = o;
}

// ---------------------------------------------------------------------------
// K0b: transpose+convert x[b][c][hw] fp32 -> xbt[b][hw][c] bf16
// ---------------------------------------------------------------------------
__global__ __launch_bounds__(256)
void k_xt(const float* __restrict__ x, ushort* __restrict__ xbt)
{
    __shared__ float tile[32][33];
    const int t = threadIdx.x;
    const int hw0 = blockIdx.x * 32;
    const int c0 = blockIdx.y * 32;
    const int b = blockIdx.z;
    const float* xb = x + ((size_t)b * Cc + c0) * HW + hw0;
    const int tx = t & 31, ty = t >> 5;
    #pragma unroll
    for (int r = 0; r < 4; r++) {
        int c = ty + r * 8;
        tile[c][tx] = xb[(size_t)c * HW + tx];
    }
    __syncthreads();
    const int hwl = t >> 3, c4 = (t & 7) * 4;
    ushort4 o = { f2bf(tile[c4 + 0][hwl]), f2bf(tile[c4 + 1][hwl]),
                  f2bf(tile[c4 + 2][hwl]), f2bf(tile[c4 + 3][hwl]) };
    *(ushort4*)&xbt[((size_t)b * HW + hw0 + hwl) * Cc + c0 + c4] = o;
}

// ---------------------------------------------------------------------------
// K1: efp[b][p][pix][c] (bf16) = ef_w @ x + ef_b.
// Barrier-free K-loop: A (weights [n][k]) and B (xT [pix][k]) fragments are
// 16B-contiguous in global — load direct, MFMA, no LDS staging.
// One barrier only for the epilogue [pix][ch] transpose.
// ---------------------------------------------------------------------------
__global__ __launch_bounds__(256)
void k_ef(const ushort* __restrict__ xbt, const ushort* __restrict__ wbe,
          const float* __restrict__ efb, ushort* __restrict__ efp)
{
    __shared__ ushort Ts[64 * 72];      // epilogue transpose [pix][ch]
    const int t = threadIdx.x;
    const int w = t >> 6, ln = t & 63;
    const int quad = ln >> 4, l16 = ln & 15;
    const int wn = w & 1, wp = w >> 1;
    const int pixb = blockIdx.x * 64;
    const int nb = blockIdx.y * 64;
    const int b = blockIdx.z;
    const int n0 = nb + wn * 32;
    const int pix0 = pixb + wp * 32;

    const ushort* Ab = wbe + (size_t)(n0 + l16) * 256 + quad * 8;
    const ushort* Bb = xbt + (size_t)b * HW * Cc + quad * 8;
    size_t px[2];
    #pragma unroll
    for (int pt = 0; pt < 2; pt++) {
        int pq = pix0 + pt * 16 + l16; if (pq > HW - 1) pq = HW - 1;
        px[pt] = (size_t)pq * Cc;
    }

    f32x4 acc[2][2];
    #pragma unroll
    for (int i = 0; i < 2; i++)
        #pragma unroll
        for (int j = 0; j < 2; j++) acc[i][j] = (f32x4){0.f, 0.f, 0.f, 0.f};

    #pragma unroll 4
    for (int kk = 0; kk < 256; kk += 32) {
        bfrag af[2], bf[2];
        af[0] = *(const bfrag*)(Ab + kk);
        af[1] = *(const bfrag*)(Ab + 16 * 256 + kk);
        bf[0] = *(const bfrag*)(Bb + px[0] + kk);
        bf[1] = *(const bfrag*)(Bb + px[1] + kk);
        #pragma unroll
        for (int dtt = 0; dtt < 2; dtt++)
            #pragma unroll
            for (int pt = 0; pt < 2; pt++)
                acc[dtt][pt] = __builtin_amdgcn_mfma_f32_16x16x32_bf16(
                    af[dtt], bf[pt], acc[dtt][pt], 0, 0, 0);
    }

    #pragma unroll
    for (int dtt = 0; dtt < 2; dtt++) {
        int chl = wn * 32 + dtt * 16 + quad * 4;
        float b0 = efb[nb + chl], b1_ = efb[nb + chl + 1];
        float b2_ = efb[nb + chl + 2], b3 = efb[nb + chl + 3];
        #pragma unroll
        for (int pt = 0; pt < 2; pt++) {
            int pixl = wp * 32 + pt * 16 + l16;
            ushort4 o = { f2bf(acc[dtt][pt][0] + b0), f2bf(acc[dtt][pt][1] + b1_),
                          f2bf(acc[dtt][pt][2] + b2_), f2bf(acc[dtt][pt][3] + b3) };
            *(ushort4*)&Ts[pixl * 72 + chl] = o;
        }
    }
    __syncthreads();
    const int p = nb >> 8, cbase = nb & 255;
    ushort* outb = efp + (size_t)((b * PTS + p) * HW) * Cc;
    #pragma unroll
    for (int r = 0; r < 2; r++) {
        int pixl = (t >> 3) + r * 32;
        int ch8 = (t & 7) * 8;
        if (pixb + pixl < HW)
            *(uint4*)&outb[(size_t)(pixb + pixl) * Cc + cbase + ch8] =
                *(const uint4*)&Ts[pixl * 72 + ch8];
    }
}

// ---------------------------------------------------------------------------
// K2: heat[b][p][pix] = exp(sum_d w2[d]*relu(D[d][pix]+b1[d]) + b2)
// Barrier-free K-loop, direct fragment loads; wave w owns d-strip w*64..+63
// for the block's 32 pixels; one barrier for the cross-wave d-reduction.
// ---------------------------------------------------------------------------
__global__ __launch_bounds__(256)
void k_heat(const ushort* __restrict__ efp, const ushort* __restrict__ wb1,
            const float* __restrict__ b1, const float* __restrict__ w2,
            const float* __restrict__ b2, float* __restrict__ heat)
{
    __shared__ float red[4][32];
    const int t = threadIdx.x;
    const int w = t >> 6, ln = t & 63;
    const int quad = ln >> 4, l16 = ln & 15;
    const int pix0 = blockIdx.x * 32;    // 475*32 == 15200 exact
    const int p = blockIdx.y;
    const int b = blockIdx.z;
    const ushort* efbp = efp + (size_t)((b * PTS + p) * HW) * Cc;
    const ushort* Ab = wb1 + (size_t)p * Cc * Cc + (size_t)(w * 64 + l16) * 256 + quad * 8;
    const ushort* Bb0 = efbp + (size_t)(pix0 + l16) * 256 + quad * 8;
    const ushort* Bb1 = Bb0 + 16 * 256;

    f32x4 acc[4][2];
    #pragma unroll
    for (int i = 0; i < 4; i++)
        #pragma unroll
        for (int j = 0; j < 2; j++) acc[i][j] = (f32x4){0.f, 0.f, 0.f, 0.f};

    #pragma unroll 2
    for (int kk = 0; kk < 256; kk += 32) {
        bfrag af[4], bf[2];
        #pragma unroll
        for (int dtt = 0; dtt < 4; dtt++)
            af[dtt] = *(const bfrag*)(Ab + (size_t)dtt * 16 * 256 + kk);
        bf[0] = *(const bfrag*)(Bb0 + kk);
        bf[1] = *(const bfrag*)(Bb1 + kk);
        #pragma unroll
        for (int dtt = 0; dtt < 4; dtt++)
            #pragma unroll
            for (int pt = 0; pt < 2; pt++)
                acc[dtt][pt] = __builtin_amdgcn_mfma_f32_16x16x32_bf16(
                    af[dtt], bf[pt], acc[dtt][pt], 0, 0, 0);
    }

    const float* b1p = b1 + p * 256;
    const float* w2p = w2 + p * 256;
    float s[2] = {0.f, 0.f};
    #pragma unroll
    for (int dtt = 0; dtt < 4; dtt++) {
        int d = w * 64 + dtt * 16 + quad * 4;
        #pragma unroll
        for (int r = 0; r < 4; r++) {
            float bb = b1p[d + r], ww = w2p[d + r];
            #pragma unroll
            for (int pt = 0; pt < 2; pt++) {
                float h = acc[dtt][pt][r] + bb;
                h = h > 0.f ? h : 0.f;
                s[pt] += ww * h;
            }
        }
    }
    #pragma unroll
    for (int pt = 0; pt < 2; pt++) {
        s[pt] += __shfl_xor(s[pt], 16);
        s[pt] += __shfl_xor(s[pt], 32);
    }
    if (ln < 16) {
        red[w][ln] = s[0];
        red[w][16 + ln] = s[1];
    }
    __syncthreads();
    if (t < 32) {
        float v = red[0][t] + red[1][t] + red[2][t] + red[3][t] + b2[p];
        heat[(size_t)(b * PTS + p) * HW + pix0 + t] = expf(v);
    }
}

// ---------------------------------------------------------------------------
// K3: deformable sampling (unchanged from round 4/6)
// ---------------------------------------------------------------------------
__global__ __launch_bounds__(256)
void k_sample(const ushort* __restrict__ efp, const float* __restrict__ heat,
              const float* __restrict__ offs, ushort* __restrict__ outs)
{
    __shared__ uint2 s_wo[32][20];
    const int t = threadIdx.x;
    const int bid = blockIdx.x;
    const int nx = (bid & 7) * 60 + (bid >> 3);
    if (nx >= 475) return;
    const int m0 = nx * 32;
    const int p = blockIdx.y;
    const int b = blockIdx.z;
    const float* heat_bp = heat + (size_t)(b * PTS + p) * HW;

    if (t < 32 * BINS) {
        int j = t / BINS, k = t % BINS;
        int hw = m0 + j;
        int hh = hw / Ww, ww = hw % Ww;
        int chy = (p * BINS + k) * 2;
        float oy = offs[((size_t)b * (PTS * BINS * 2) + chy)     * HW + hw];
        float ox = offs[((size_t)b * (PTS * BINS * 2) + chy + 1) * HW + hw];
        float ysf = (float)hh + oy;
        float xsf = (float)ww + ox;
        float y0 = floorf(ysf), x0 = floorf(xsf);
        #pragma unroll
        for (int dy = 0; dy < 2; dy++)
            #pragma unroll
            for (int dx = 0; dx < 2; dx++) {
                float yi = y0 + dy, xi = x0 + dx;
                float wgt = (1.f - fabsf(ysf - yi)) * (1.f - fabsf(xsf - xi));
                bool valid = (yi >= 0.f) && (yi <= (float)(Hh - 1)) &&
                             (xi >= 0.f) && (xi <= (float)(Ww - 1));
                int yc = (int)yi; yc = yc < 0 ? 0 : (yc > Hh - 1 ? Hh - 1 : yc);
                int xc = (int)xi; xc = xc < 0 ? 0 : (xc > Ww - 1 ? Ww - 1 : xc);
                int idx = yc * Ww + xc;
                float wh = valid ? wgt * heat_bp[idx] : 0.f;
                s_wo[j][k * 4 + dy * 2 + dx] =
                    make_uint2(__float_as_uint(wh), (unsigned)idx << 9);
            }
    }
    __syncthreads();
    if (t < 32) {
        float s = 0.f;
        #pragma unroll
        for (int u = 0; u < 20; u++) s += __uint_as_float(s_wo[t][u].x);
        float inv = 1.f / (s + EPS_DIV);
        #pragma unroll
        for (int u = 0; u < 20; u++)
            s_wo[t][u].x = __float_as_uint(__uint_as_float(s_wo[t][u].x) * inv);
    }
    __syncthreads();

    const int wv = t >> 6, ln = t & 63;
    const char* efbase = (const char*)(efp + (size_t)((b * PTS + p) * HW) * Cc)
                         + ln * 8;
    ushort* ob = outs + ((size_t)(b * HW + m0)) * (PTS * Cc) + p * Cc + ln * 4;
    #pragma unroll
    for (int i = 0; i < 8; i += 2) {
        const int j0 = wv * 8 + i, j1 = j0 + 1;
        float a0[4] = {0.f, 0.f, 0.f, 0.f};
        float a1[4] = {0.f, 0.f, 0.f, 0.f};
        #pragma unroll
        for (int u = 0; u < 20; u++) {
            uint2 wo0 = s_wo[j0][u];
            uint2 wo1 = s_wo[j1][u];
            uint2 v0 = *(const uint2*)(efbase + wo0.y);
            uint2 v1 = *(const uint2*)(efbase + wo1.y);
            float w0 = __uint_as_float(wo0.x);
            float w1 = __uint_as_float(wo1.x);
            a0[0] += w0 * bflo(v0.x); a0[1] += w0 * bfhi(v0.x);
            a0[2] += w0 * bflo(v0.y); a0[3] += w0 * bfhi(v0.y);
            a1[0] += w1 * bflo(v1.x); a1[1] += w1 * bfhi(v1.x);
            a1[2] += w1 * bflo(v1.y); a1[3] += w1 * bfhi(v1.y);
        }
        uint2 o0 = make_uint2(pack2(a0[0], a0[1]), pack2(a0[2], a0[3]));
        uint2 o1 = make_uint2(pack2(a1[0], a1[1]), pack2(a1[2], a1[3]));
        *(uint2*)(ob + (size_t)j0 * (PTS * Cc)) = o0;
        *(uint2*)(ob + (size_t)j1 * (PTS * Cc)) = o1;
    }
}

// ---------------------------------------------------------------------------
// K4: out[b][c][pix] (fp32) = merge_w @ outs + merge_b, + fused GN partials.
// Fully barrier-free, zero LDS: direct fragment loads from global.
// ---------------------------------------------------------------------------
__global__ __launch_bounds__(256)
void k_merge(const ushort* __restrict__ outs, const ushort* __restrict__ wbm,
             const float* __restrict__ mb, float* __restrict__ out,
             float* __restrict__ part)
{
    const int t = threadIdx.x;
    const int w = t >> 6, ln = t & 63;
    const int quad = ln >> 4, l16 = ln & 15;
    const int wn = w & 1, wp = w >> 1;
    const int pix0 = blockIdx.x * 64 + wp * 32;
    const int n0 = blockIdx.y * 64 + wn * 32;
    const int b = blockIdx.z;
    const ushort* ob = outs + (size_t)b * HW * (PTS * Cc) + quad * 8;
    const ushort* Ab = wbm + (size_t)(n0 + l16) * 512 + quad * 8;

    size_t px[2];
    #pragma unroll
    for (int pt = 0; pt < 2; pt++) {
        int pq = pix0 + pt * 16 + l16; if (pq > HW - 1) pq = HW - 1;
        px[pt] = (size_t)pq * (PTS * Cc);
    }

    f32x4 acc[2][2];
    #pragma unroll
    for (int i = 0; i < 2; i++)
        #pragma unroll
        for (int j = 0; j < 2; j++) acc[i][j] = (f32x4){0.f, 0.f, 0.f, 0.f};

    #pragma unroll 4
    for (int kk = 0; kk < 512; kk += 32) {
        bfrag af[2], bf[2];
        af[0] = *(const bfrag*)(Ab + kk);
        af[1] = *(const bfrag*)(Ab + 16 * 512 + kk);
        bf[0] = *(const bfrag*)(ob + px[0] + kk);
        bf[1] = *(const bfrag*)(ob + px[1] + kk);
        #pragma unroll
        for (int dtt = 0; dtt < 2; dtt++)
            #pragma unroll
            for (int pt = 0; pt < 2; pt++)
                acc[dtt][pt] = __builtin_amdgcn_mfma_f32_16x16x32_bf16(
                    af[dtt], bf[pt], acc[dtt][pt], 0, 0, 0);
    }

    #pragma unroll
    for (int dtt = 0; dtt < 2; dtt++) {
        int ch = n0 + dtt * 16 + quad * 4;
        float bias[4];
        #pragma unroll
        for (int r = 0; r < 4; r++) bias[r] = mb[ch + r];
        float sacc = 0.f, qacc = 0.f;
        #pragma unroll
        for (int pt = 0; pt < 2; pt++) {
            int pix = pix0 + pt * 16 + l16;
            if (pix < HW) {
                #pragma unroll
                for (int r = 0; r < 4; r++) {
                    float v = acc[dtt][pt][r] + bias[r];
                    out[((size_t)b * Cc + ch + r) * HW + pix] = v;
                    sacc += v; qacc += v * v;
                }
            }
        }
        #pragma unroll
        for (int off = 1; off <= 16; off <<= 1) {
            sacc += __shfl_xor(sacc, off);
            qacc += __shfl_xor(qacc, off);
        }
        if ((ln & 31) == 0) {
            int g = (n0 >> 3) + dtt * 2 + (ln >> 5);
            atomicAdd(&part[(b * 32 + g) * 2 + 0], sacc);
            atomicAdd(&part[(b * 32 + g) * 2 + 1], qacc);
        }
    }
}

// ---------------------------------------------------------------------------
// K5: finalize GN stats (64 groups total)
// ---------------------------------------------------------------------------
__global__ __launch_bounds__(64)
void k_gnfinal(const float* __restrict__ part, float* __restrict__ statf)
{
    int i = threadIdx.x;
    float s = part[i * 2 + 0], q = part[i * 2 + 1];
    const float n = 8.f * HW;
    float mean = s / n;
    float var  = q / n - mean * mean;
    statf[i * 2 + 0] = mean;
    statf[i * 2 + 1] = rsqrtf(var + GN_EPS);
}

// ---------------------------------------------------------------------------
// K6: apply GN scale/shift + ReLU in place
// ---------------------------------------------------------------------------
__global__ __launch_bounds__(256)
void k_gnapply(float* __restrict__ out, const float* __restrict__ statf,
               const float* __restrict__ gg, const float* __restrict__ gb)
{
    const int i4 = blockIdx.x * 256 + threadIdx.x;
    const int total4 = Bx * Cc * HW / 4;
    if (i4 >= total4) return;
    const int i = i4 * 4;
    const int CHW = Cc * HW;
    const int b = i / CHW;
    const int r = i - b * CHW;
    const int c = r / HW;
    const int g = c >> 3;
    float mean = statf[(b * 32 + g) * 2 + 0];
    float istd = statf[(b * 32 + g) * 2 + 1];
    float sc = istd * gg[c];
    float sh = gb[c] - mean * sc;
    float4 v = *(float4*)(out + i);
    v.x = fmaxf(v.x * sc + sh, 0.f);
    v.y = fmaxf(v.y * sc + sh, 0.f);
    v.z = fmaxf(v.z * sc + sh, 0.f);
    v.w = fmaxf(v.w * sc + sh, 0.f);
    *(float4*)(out + i) = v;
}

// ---------------------------------------------------------------------------
extern "C" void kernel_launch(void* const* d_in, const int* in_sizes, int n_in,
                              void* d_out, int out_size, void* d_ws, size_t ws_size,
                              hipStream_t stream)
{
    const float* x    = (const float*)d_in[0];
    const float* offs = (const float*)d_in[1];
    const float* efw  = (const float*)d_in[2];
    const float* efb  = (const float*)d_in[3];
    const float* w1   = (const float*)d_in[4];
    const float* b1   = (const float*)d_in[5];
    const float* w2   = (const float*)d_in[6];
    const float* b2   = (const float*)d_in[7];
    const float* mw   = (const float*)d_in[8];
    const float* mb   = (const float*)d_in[9];
    const float* gg   = (const float*)d_in[10];
    const float* gb   = (const float*)d_in[11];
    float* out = (float*)d_out;

    ushort* wb    = (ushort*)d_ws;
    ushort* wbe   = wb;                          // 131072
    ushort* wb1   = wb + 131072;
    ushort* wbm   = wb + 262144;
    ushort* efp   = wb + 393216;                 // B*P*HW*C bf16
    ushort* outsb = efp + (size_t)Bx * PTS * HW * Cc;
    float*  heat  = (float*)(outsb + (size_t)Bx * HW * PTS * Cc);
    float*  part  = heat + (size_t)Bx * PTS * HW;   // 128 floats
    float*  statf = part + 128;                     // 128 floats
    ushort* xbt   = (ushort*)(statf + 128);         // B*HW*C bf16

    dim3 blk(256);
    k_wconv  <<<dim3(384),          blk, 0, stream>>>(efw, w1, mw, wb, part);
    k_xt     <<<dim3(475, 8, Bx),   blk, 0, stream>>>(x, xbt);
    k_ef     <<<dim3(238, 8, Bx),   blk, 0, stream>>>(xbt, wbe, efb, efp);
    k_heat   <<<dim3(475, PTS, Bx), blk, 0, stream>>>(efp, wb1, b1, w2, b2, heat);
    k_sample <<<dim3(480, PTS, Bx), blk, 0, stream>>>(efp, heat, offs, outsb);
    k_merge  <<<dim3(238, 4, Bx),   blk, 0, stream>>>(outsb, wbm, mb, out, part);
    k_gnfinal<<<dim3(1), dim3(64),  0, stream>>>(part, statf);
    k_gnapply<<<dim3(Bx * Cc * HW / 4 / 256), blk, 0, stream>>>(out, statf, gg, gb);
}

// Round 8
// 367.185 us; speedup vs baseline: 1.1944x; 1.1944x over previous
//
#include <hip/hip_runtime.h>

#define BINS 5
#define PTS  2
constexpr int Bx = 2, Cc = 256, Hh = 100, Ww = 152;
constexpr int HW = Hh * Ww;          // 15200
constexpr float EPS_DIV = 1e-6f;
constexpr float GN_EPS  = 1e-5f;

typedef __attribute__((ext_vector_type(8))) short bfrag;   // 8 bf16 (4 VGPRs)
typedef __attribute__((ext_vector_type(4))) float f32x4;   // MFMA C/D

__device__ __forceinline__ ushort f2bf(float f) {
    union { float f; unsigned u; } v; v.f = f;
    unsigned r = v.u + 0x7fffu + ((v.u >> 16) & 1u);
    return (ushort)(r >> 16);
}
__device__ __forceinline__ float bflo(unsigned u) {
    return __uint_as_float(u << 16);
}
__device__ __forceinline__ float bfhi(unsigned u) {
    return __uint_as_float(u & 0xffff0000u);
}
__device__ __forceinline__ unsigned pack2(float a, float b) {
    return (unsigned)f2bf(a) | ((unsigned)f2bf(b) << 16);
}

// ---------------------------------------------------------------------------
// K0: convert ef_w, hm1_w, merge_w to bf16 (each 131072 elems) + zero GN parts
// ---------------------------------------------------------------------------
__global__ __launch_bounds__(256)
void k_wconv(const float* __restrict__ efw, const float* __restrict__ w1,
             const float* __restrict__ mw, ushort* __restrict__ wb,
             float* __restrict__ part)
{
    if (blockIdx.x == 0 && threadIdx.x < 128) part[threadIdx.x] = 0.f;
    int gid = blockIdx.x * 256 + threadIdx.x;
    int e = gid * 4;
    int arr = e >> 17, off = e & 131071;
    const float* src = arr == 0 ? efw : (arr == 1 ? w1 : mw);
    float4 v = *(const float4*)(src + off);
    ushort4 o = { f2bf(v.x), f2bf(v.y), f2bf(v.z), f2bf(v.w) };
    *(ushort4*)(wb + e) = o;
}

// ---------------------------------------------------------------------------
// K0b: transpose+convert x[b][c][hw] fp32 -> xbt[b][hw][c] bf16
// ---------------------------------------------------------------------------
__global__ __launch_bounds__(256)
void k_xt(const float* __restrict__ x, ushort* __restrict__ xbt)
{
    __shared__ float tile[32][33];
    const int t = threadIdx.x;
    const int hw0 = blockIdx.x * 32;
    const int c0 = blockIdx.y * 32;
    const int b = blockIdx.z;
    const float* xb = x + ((size_t)b * Cc + c0) * HW + hw0;
    const int tx = t & 31, ty = t >> 5;
    #pragma unroll
    for (int r = 0; r < 4; r++) {
        int c = ty + r * 8;
        tile[c][tx] = xb[(size_t)c * HW + tx];
    }
    __syncthreads();
    const int hwl = t >> 3, c4 = (t & 7) * 4;
    ushort4 o = { f2bf(tile[c4 + 0][hwl]), f2bf(tile[c4 + 1][hwl]),
                  f2bf(tile[c4 + 2][hwl]), f2bf(tile[c4 + 3][hwl]) };
    *(ushort4*)&xbt[((size_t)b * HW + hw0 + hwl) * Cc + c0 + c4] = o;
}

// ---------------------------------------------------------------------------
// K1: FUSED expand_feat + heatmap.  Block = 32 pixels x all 512 channels.
// ef-GEMM: B (x-strip) staged once in LDS; A (ef_w) direct from L2-hot global
// (16 fully-consumed 64B lines per load instr).  ef output lives in LDS Es ->
// heat-GEMM reads B from Es (efp never re-read from HBM).  Writes efp + heat.
// ---------------------------------------------------------------------------
__global__ __launch_bounds__(256)
void k_efheat(const ushort* __restrict__ xbt, const ushort* __restrict__ wbe,
              const float* __restrict__ efb, const ushort* __restrict__ wb1,
              const float* __restrict__ b1, const float* __restrict__ w2,
              const float* __restrict__ b2, ushort* __restrict__ efp,
              float* __restrict__ heat)
{
    __shared__ ushort Xs[32 * 264];      // [pix][k]   stride 264 (2-way free)
    __shared__ ushort Es[32 * 520];      // [pix][ch]  stride 520 (2-way free)
    __shared__ float red[4][32];
    const int t = threadIdx.x;
    const int w = t >> 6, ln = t & 63;
    const int quad = ln >> 4, l16 = ln & 15;
    const int pix0 = blockIdx.x * 32;    // 475*32 == 15200 exact
    const int b = blockIdx.y;

    // stage x strip: 32 pix x 256 k bf16
    {
        const ushort* src = xbt + ((size_t)b * HW + pix0) * 256;
        int row = t >> 3, c8 = (t & 7) * 8;
        #pragma unroll
        for (int r = 0; r < 4; r++)
            *(uint4*)&Xs[row * 264 + c8 + r * 64] =
                *(const uint4*)&src[(size_t)row * 256 + c8 + r * 64];
    }
    __syncthreads();

    // ef GEMM: wave w owns channels w*128 .. w*128+127
    f32x4 acc[8][2];
    #pragma unroll
    for (int i = 0; i < 8; i++)
        #pragma unroll
        for (int j = 0; j < 2; j++) acc[i][j] = (f32x4){0.f, 0.f, 0.f, 0.f};

    const ushort* Ab = wbe + (size_t)(w * 128 + l16) * 256 + quad * 8;
    #pragma unroll 2
    for (int kk = 0; kk < 256; kk += 32) {
        bfrag bf[2];
        bf[0] = *(const bfrag*)&Xs[l16 * 264 + quad * 8 + kk];
        bf[1] = *(const bfrag*)&Xs[(16 + l16) * 264 + quad * 8 + kk];
        #pragma unroll
        for (int nf = 0; nf < 8; nf++) {
            bfrag af = *(const bfrag*)(Ab + (size_t)nf * 16 * 256 + kk);
            acc[nf][0] = __builtin_amdgcn_mfma_f32_16x16x32_bf16(af, bf[0], acc[nf][0], 0, 0, 0);
            acc[nf][1] = __builtin_amdgcn_mfma_f32_16x16x32_bf16(af, bf[1], acc[nf][1], 0, 0, 0);
        }
    }

    // ef epilogue: bias + bf16 -> Es[pix][ch]
    #pragma unroll
    for (int nf = 0; nf < 8; nf++) {
        int ch = w * 128 + nf * 16 + quad * 4;
        float b0 = efb[ch], b1_ = efb[ch + 1], b2_ = efb[ch + 2], b3_ = efb[ch + 3];
        #pragma unroll
        for (int pt = 0; pt < 2; pt++) {
            int pixl = pt * 16 + l16;
            ushort4 o = { f2bf(acc[nf][pt][0] + b0), f2bf(acc[nf][pt][1] + b1_),
                          f2bf(acc[nf][pt][2] + b2_), f2bf(acc[nf][pt][3] + b3_) };
            *(ushort4*)&Es[pixl * 520 + ch] = o;
        }
    }
    __syncthreads();

    // write efp (coalesced from Es)
    {
        int row = t >> 3, c8 = (t & 7) * 8;
        #pragma unroll
        for (int r = 0; r < 8; r++) {
            int col = c8 + r * 64;           // 0..511
            int p = col >> 8, c = col & 255;
            *(uint4*)&efp[((size_t)((b * PTS + p) * HW) + pix0 + row) * 256 + c] =
                *(const uint4*)&Es[row * 520 + col];
        }
    }

    // heat GEMM: wave w -> p = w&1, d-strip = (w>>1)*128
    const int p = w & 1, ds = w >> 1;
    const ushort* Ah = wb1 + (size_t)p * 65536 + (size_t)(ds * 128 + l16) * 256 + quad * 8;
    const int ebase = p * 256;
    f32x4 hacc[8][2];
    #pragma unroll
    for (int i = 0; i < 8; i++)
        #pragma unroll
        for (int j = 0; j < 2; j++) hacc[i][j] = (f32x4){0.f, 0.f, 0.f, 0.f};

    #pragma unroll 2
    for (int kk = 0; kk < 256; kk += 32) {
        bfrag bf[2];
        bf[0] = *(const bfrag*)&Es[l16 * 520 + ebase + quad * 8 + kk];
        bf[1] = *(const bfrag*)&Es[(16 + l16) * 520 + ebase + quad * 8 + kk];
        #pragma unroll
        for (int df = 0; df < 8; df++) {
            bfrag af = *(const bfrag*)(Ah + (size_t)df * 16 * 256 + kk);
            hacc[df][0] = __builtin_amdgcn_mfma_f32_16x16x32_bf16(af, bf[0], hacc[df][0], 0, 0, 0);
            hacc[df][1] = __builtin_amdgcn_mfma_f32_16x16x32_bf16(af, bf[1], hacc[df][1], 0, 0, 0);
        }
    }

    const float* b1p = b1 + p * 256;
    const float* w2p = w2 + p * 256;
    float s[2] = {0.f, 0.f};
    #pragma unroll
    for (int df = 0; df < 8; df++) {
        int d = ds * 128 + df * 16 + quad * 4;
        #pragma unroll
        for (int r = 0; r < 4; r++) {
            float bb = b1p[d + r], ww = w2p[d + r];
            #pragma unroll
            for (int pt = 0; pt < 2; pt++) {
                float h = hacc[df][pt][r] + bb;
                h = h > 0.f ? h : 0.f;
                s[pt] += ww * h;
            }
        }
    }
    #pragma unroll
    for (int pt = 0; pt < 2; pt++) {
        s[pt] += __shfl_xor(s[pt], 16);
        s[pt] += __shfl_xor(s[pt], 32);
    }
    if (ln < 16) { red[w][l16] = s[0]; red[w][16 + l16] = s[1]; }
    __syncthreads();
    if (t < 64) {
        int pp = t >> 5, j = t & 31;
        float v = red[pp][j] + red[pp + 2][j] + b2[pp];
        heat[(size_t)(b * PTS + pp) * HW + pix0 + j] = expf(v);
    }
}

// ---------------------------------------------------------------------------
// K2: FUSED sampling + merge.  Block = 32 pixels, BOTH points.
// Sampled tile (32 pix x 512) goes to LDS Os (outs never materialized),
// then merge-GEMM (A = mw direct L2-hot, B from LDS) + fused GN partials.
// ---------------------------------------------------------------------------
__global__ __launch_bounds__(256)
void k_samerge(const ushort* __restrict__ efp, const float* __restrict__ heat,
               const float* __restrict__ offs, const ushort* __restrict__ wbm,
               const float* __restrict__ mb, float* __restrict__ out,
               float* __restrict__ part)
{
    __shared__ uint2 s_wo[2][32][20];    // {bitcast(weight), byteoff = idx<<9}
    __shared__ ushort Os[32 * 520];      // [pix][k=512] stride 520 (2-way free)
    const int t = threadIdx.x;
    const int bid = blockIdx.x;
    const int nx = (bid & 7) * 60 + (bid >> 3);   // XCD-contiguous bands
    if (nx >= 475) return;
    const int m0 = nx * 32;
    const int b = blockIdx.y;

    // phase 1: bilinear weights * heat for both p (320 items, 256 threads)
    for (int it = t; it < 320; it += 256) {
        int j = it / 10, rem = it - j * 10;
        int p = rem / 5, k = rem - p * 5;
        const float* heat_bp = heat + (size_t)(b * PTS + p) * HW;
        int hw = m0 + j;
        int hh = hw / Ww, ww = hw % Ww;
        int chy = (p * BINS + k) * 2;
        float oy = offs[((size_t)b * (PTS * BINS * 2) + chy)     * HW + hw];
        float ox = offs[((size_t)b * (PTS * BINS * 2) + chy + 1) * HW + hw];
        float ysf = (float)hh + oy;
        float xsf = (float)ww + ox;
        float y0 = floorf(ysf), x0 = floorf(xsf);
        #pragma unroll
        for (int dy = 0; dy < 2; dy++)
            #pragma unroll
            for (int dx = 0; dx < 2; dx++) {
                float yi = y0 + dy, xi = x0 + dx;
                float wgt = (1.f - fabsf(ysf - yi)) * (1.f - fabsf(xsf - xi));
                bool valid = (yi >= 0.f) && (yi <= (float)(Hh - 1)) &&
                             (xi >= 0.f) && (xi <= (float)(Ww - 1));
                int yc = (int)yi; yc = yc < 0 ? 0 : (yc > Hh - 1 ? Hh - 1 : yc);
                int xc = (int)xi; xc = xc < 0 ? 0 : (xc > Ww - 1 ? Ww - 1 : xc);
                int idx = yc * Ww + xc;
                float wh = valid ? wgt * heat_bp[idx] : 0.f;
                s_wo[p][j][k * 4 + dy * 2 + dx] =
                    make_uint2(__float_as_uint(wh), (unsigned)idx << 9);
            }
    }
    __syncthreads();
    if (t < 64) {
        int p = t >> 5, j = t & 31;
        float s = 0.f;
        #pragma unroll
        for (int u = 0; u < 20; u++) s += __uint_as_float(s_wo[p][j][u].x);
        float inv = 1.f / (s + EPS_DIV);
        #pragma unroll
        for (int u = 0; u < 20; u++)
            s_wo[p][j][u].x = __float_as_uint(__uint_as_float(s_wo[p][j][u].x) * inv);
    }
    __syncthreads();

    // phase 2: gather both p -> Os (lane = 4-channel group, 2-pixel unroll)
    const int wv = t >> 6, ln = t & 63;
    #pragma unroll
    for (int p = 0; p < 2; p++) {
        const char* efbase = (const char*)(efp + (size_t)((b * PTS + p) * HW) * Cc)
                             + ln * 8;
        #pragma unroll
        for (int i = 0; i < 8; i += 2) {
            const int j0 = wv * 8 + i, j1 = j0 + 1;
            float a0[4] = {0.f, 0.f, 0.f, 0.f};
            float a1[4] = {0.f, 0.f, 0.f, 0.f};
            #pragma unroll
            for (int u = 0; u < 20; u++) {
                uint2 wo0 = s_wo[p][j0][u];
                uint2 wo1 = s_wo[p][j1][u];
                uint2 v0 = *(const uint2*)(efbase + wo0.y);
                uint2 v1 = *(const uint2*)(efbase + wo1.y);
                float w0 = __uint_as_float(wo0.x);
                float w1 = __uint_as_float(wo1.x);
                a0[0] += w0 * bflo(v0.x); a0[1] += w0 * bfhi(v0.x);
                a0[2] += w0 * bflo(v0.y); a0[3] += w0 * bfhi(v0.y);
                a1[0] += w1 * bflo(v1.x); a1[1] += w1 * bfhi(v1.x);
                a1[2] += w1 * bflo(v1.y); a1[3] += w1 * bfhi(v1.y);
            }
            *(uint2*)&Os[j0 * 520 + p * 256 + ln * 4] =
                make_uint2(pack2(a0[0], a0[1]), pack2(a0[2], a0[3]));
            *(uint2*)&Os[j1 * 520 + p * 256 + ln * 4] =
                make_uint2(pack2(a1[0], a1[1]), pack2(a1[2], a1[3]));
        }
    }
    __syncthreads();

    // phase 3: merge GEMM, wave wv owns 64 output channels
    const int quad = ln >> 4, l16 = ln & 15;
    const ushort* Am = wbm + (size_t)(wv * 64 + l16) * 512 + quad * 8;
    f32x4 macc[4][2];
    #pragma unroll
    for (int i = 0; i < 4; i++)
        #pragma unroll
        for (int j = 0; j < 2; j++) macc[i][j] = (f32x4){0.f, 0.f, 0.f, 0.f};

    #pragma unroll 2
    for (int kk = 0; kk < 512; kk += 32) {
        bfrag bf[2];
        bf[0] = *(const bfrag*)&Os[l16 * 520 + quad * 8 + kk];
        bf[1] = *(const bfrag*)&Os[(16 + l16) * 520 + quad * 8 + kk];
        #pragma unroll
        for (int nf = 0; nf < 4; nf++) {
            bfrag af = *(const bfrag*)(Am + (size_t)nf * 16 * 512 + kk);
            macc[nf][0] = __builtin_amdgcn_mfma_f32_16x16x32_bf16(af, bf[0], macc[nf][0], 0, 0, 0);
            macc[nf][1] = __builtin_amdgcn_mfma_f32_16x16x32_bf16(af, bf[1], macc[nf][1], 0, 0, 0);
        }
    }

    #pragma unroll
    for (int nf = 0; nf < 4; nf++) {
        int ch = wv * 64 + nf * 16 + quad * 4;
        float bias[4];
        #pragma unroll
        for (int r = 0; r < 4; r++) bias[r] = mb[ch + r];
        float sacc = 0.f, qacc = 0.f;
        #pragma unroll
        for (int pt = 0; pt < 2; pt++) {
            int pix = m0 + pt * 16 + l16;
            #pragma unroll
            for (int r = 0; r < 4; r++) {
                float v = macc[nf][pt][r] + bias[r];
                out[((size_t)b * Cc + ch + r) * HW + pix] = v;
                sacc += v; qacc += v * v;
            }
        }
        #pragma unroll
        for (int off = 1; off <= 16; off <<= 1) {
            sacc += __shfl_xor(sacc, off);
            qacc += __shfl_xor(qacc, off);
        }
        if ((ln & 31) == 0) {
            int g = wv * 8 + nf * 2 + (ln >> 5);
            atomicAdd(&part[(b * 32 + g) * 2 + 0], sacc);
            atomicAdd(&part[(b * 32 + g) * 2 + 1], qacc);
        }
    }
}

// ---------------------------------------------------------------------------
// K5: finalize GN stats (64 groups total)
// ---------------------------------------------------------------------------
__global__ __launch_bounds__(64)
void k_gnfinal(const float* __restrict__ part, float* __restrict__ statf)
{
    int i = threadIdx.x;
    float s = part[i * 2 + 0], q = part[i * 2 + 1];
    const float n = 8.f * HW;
    float mean = s / n;
    float var  = q / n - mean * mean;
    statf[i * 2 + 0] = mean;
    statf[i * 2 + 1] = rsqrtf(var + GN_EPS);
}

// ---------------------------------------------------------------------------
// K6: apply GN scale/shift + ReLU in place
// ---------------------------------------------------------------------------
__global__ __launch_bounds__(256)
void k_gnapply(float* __restrict__ out, const float* __restrict__ statf,
               const float* __restrict__ gg, const float* __restrict__ gb)
{
    const int i4 = blockIdx.x * 256 + threadIdx.x;
    const int total4 = Bx * Cc * HW / 4;
    if (i4 >= total4) return;
    const int i = i4 * 4;
    const int CHW = Cc * HW;
    const int b = i / CHW;
    const int r = i - b * CHW;
    const int c = r / HW;
    const int g = c >> 3;
    float mean = statf[(b * 32 + g) * 2 + 0];
    float istd = statf[(b * 32 + g) * 2 + 1];
    float sc = istd * gg[c];
    float sh = gb[c] - mean * sc;
    float4 v = *(float4*)(out + i);
    v.x = fmaxf(v.x * sc + sh, 0.f);
    v.y = fmaxf(v.y * sc + sh, 0.f);
    v.z = fmaxf(v.z * sc + sh, 0.f);
    v.w = fmaxf(v.w * sc + sh, 0.f);
    *(float4*)(out + i) = v;
}

// ---------------------------------------------------------------------------
extern "C" void kernel_launch(void* const* d_in, const int* in_sizes, int n_in,
                              void* d_out, int out_size, void* d_ws, size_t ws_size,
                              hipStream_t stream)
{
    const float* x    = (const float*)d_in[0];
    const float* offs = (const float*)d_in[1];
    const float* efw  = (const float*)d_in[2];
    const float* efb  = (const float*)d_in[3];
    const float* w1   = (const float*)d_in[4];
    const float* b1   = (const float*)d_in[5];
    const float* w2   = (const float*)d_in[6];
    const float* b2   = (const float*)d_in[7];
    const float* mw   = (const float*)d_in[8];
    const float* mb   = (const float*)d_in[9];
    const float* gg   = (const float*)d_in[10];
    const float* gb   = (const float*)d_in[11];
    float* out = (float*)d_out;

    ushort* wb    = (ushort*)d_ws;
    ushort* wbe   = wb;                          // 131072
    ushort* wb1   = wb + 131072;
    ushort* wbm   = wb + 262144;
    ushort* efp   = wb + 393216;                 // B*P*HW*C bf16
    ushort* xbt   = efp + (size_t)Bx * PTS * HW * Cc;   // B*HW*C bf16
    float*  heat  = (float*)(xbt + (size_t)Bx * HW * Cc);
    float*  part  = heat + (size_t)Bx * PTS * HW;   // 128 floats
    float*  statf = part + 128;                     // 128 floats

    dim3 blk(256);
    k_wconv  <<<dim3(384),          blk, 0, stream>>>(efw, w1, mw, wb, part);
    k_xt     <<<dim3(475, 8, Bx),   blk, 0, stream>>>(x, xbt);
    k_efheat <<<dim3(475, Bx),      blk, 0, stream>>>(xbt, wbe, efb, wb1, b1, w2, b2, efp, heat);
    k_samerge<<<dim3(480, Bx),      blk, 0, stream>>>(efp, heat, offs, wbm, mb, out, part);
    k_gnfinal<<<dim3(1), dim3(64),  0, stream>>>(part, statf);
    k_gnapply<<<dim3(Bx * Cc * HW / 4 / 256), blk, 0, stream>>>(out, statf, gg, gb);
}

// Round 9
// 214.345 us; speedup vs baseline: 2.0460x; 1.7131x over previous
//
#include <hip/hip_runtime.h>

#define BINS 5
#define PTS  2
constexpr int Bx = 2, Cc = 256, Hh = 100, Ww = 152;
constexpr int HW = Hh * Ww;          // 15200
constexpr int NTILE = 238;           // merge pixel tiles (64 px each)
constexpr float EPS_DIV = 1e-6f;
constexpr float GN_EPS  = 1e-5f;

typedef __attribute__((ext_vector_type(8))) short bfrag;   // 8 bf16 (4 VGPRs)
typedef __attribute__((ext_vector_type(4))) float f32x4;   // MFMA C/D

__device__ __forceinline__ ushort f2bf(float f) {
    union { float f; unsigned u; } v; v.f = f;
    unsigned r = v.u + 0x7fffu + ((v.u >> 16) & 1u);
    return (ushort)(r >> 16);
}
__device__ __forceinline__ float bflo(unsigned u) {
    return __uint_as_float(u << 16);
}
__device__ __forceinline__ float bfhi(unsigned u) {
    return __uint_as_float(u & 0xffff0000u);
}
__device__ __forceinline__ unsigned pack2(float a, float b) {
    return (unsigned)f2bf(a) | ((unsigned)f2bf(b) << 16);
}

// ---------------------------------------------------------------------------
// K0: convert ef_w, hm1_w, merge_w to bf16 (each 131072 elems)
// ---------------------------------------------------------------------------
__global__ __launch_bounds__(256)
void k_wconv(const float* __restrict__ efw, const float* __restrict__ w1,
             const float* __restrict__ mw, ushort* __restrict__ wb)
{
    int gid = blockIdx.x * 256 + threadIdx.x;
    int e = gid * 4;
    int arr = e >> 17, off = e & 131071;
    const float* src = arr == 0 ? efw : (arr == 1 ? w1 : mw);
    float4 v = *(const float4*)(src + off);
    ushort4 o = { f2bf(v.x), f2bf(v.y), f2bf(v.z), f2bf(v.w) };
    *(ushort4*)(wb + e) = o;
}

// ---------------------------------------------------------------------------
// K1: efp[b][p][pix][c] (bf16) = ef_w @ x + ef_b.  (round-4 proven structure)
// ---------------------------------------------------------------------------
__global__ __launch_bounds__(256)
void k_ef(const float* __restrict__ x, const ushort* __restrict__ wbe,
          const float* __restrict__ efb, ushort* __restrict__ efp)
{
    __shared__ ushort As[128 * 72];     // [n][k] pad 72
    __shared__ ushort Bs[64 * 72];      // [pix][k]
    const int t = threadIdx.x;
    const int wv = t >> 6, ln = t & 63;
    const int quad = ln >> 4, l16 = ln & 15;
    const int pix0 = blockIdx.x * 64;
    const int n0 = blockIdx.y * 128;
    const int b = blockIdx.z;
    const float* xb = x + (size_t)b * Cc * HW;

    f32x4 acc[2][4];
    #pragma unroll
    for (int i = 0; i < 2; i++)
        #pragma unroll
        for (int j = 0; j < 4; j++) acc[i][j] = (f32x4){0.f, 0.f, 0.f, 0.f};

    const int arow = t >> 3, acol = (t & 7) * 8;
    const int bpix = t & 63, bkg = (t >> 6) * 8;
    int pp = pix0 + bpix; if (pp > HW - 1) pp = HW - 1;

    for (int k0 = 0; k0 < 256; k0 += 64) {
        #pragma unroll
        for (int r = 0; r < 4; r++) {
            int row = arow + r * 32;
            *(uint4*)&As[row * 72 + acol] =
                *(const uint4*)&wbe[(size_t)(n0 + row) * 256 + k0 + acol];
        }
        #pragma unroll
        for (int r = 0; r < 2; r++) {
            int kc = bkg + r * 32;
            union { ushort s[8]; uint4 v; } tmp;
            #pragma unroll
            for (int j = 0; j < 8; j++)
                tmp.s[j] = f2bf(xb[(size_t)(k0 + kc + j) * HW + pp]);
            *(uint4*)&Bs[bpix * 72 + kc] = tmp.v;
        }
        __syncthreads();
        #pragma unroll
        for (int kk = 0; kk < 64; kk += 32) {
            bfrag af[2], bfr[4];
            #pragma unroll
            for (int dt = 0; dt < 2; dt++)
                af[dt] = *(const bfrag*)&As[(wv * 32 + dt * 16 + l16) * 72 + kk + quad * 8];
            #pragma unroll
            for (int pt = 0; pt < 4; pt++)
                bfr[pt] = *(const bfrag*)&Bs[(pt * 16 + l16) * 72 + kk + quad * 8];
            #pragma unroll
            for (int dt = 0; dt < 2; dt++)
                #pragma unroll
                for (int pt = 0; pt < 4; pt++)
                    acc[dt][pt] = __builtin_amdgcn_mfma_f32_16x16x32_bf16(
                        af[dt], bfr[pt], acc[dt][pt], 0, 0, 0);
        }
        __syncthreads();
    }

    float bias[2][4];
    #pragma unroll
    for (int dt = 0; dt < 2; dt++)
        #pragma unroll
        for (int r = 0; r < 4; r++)
            bias[dt][r] = efb[n0 + wv * 32 + dt * 16 + quad * 4 + r];
    #pragma unroll
    for (int dt = 0; dt < 2; dt++)
        #pragma unroll
        for (int pt = 0; pt < 4; pt++) {
            int pix = pt * 16 + l16;
            int ch = wv * 32 + dt * 16 + quad * 4;
            ushort4 o = { f2bf(acc[dt][pt][0] + bias[dt][0]),
                          f2bf(acc[dt][pt][1] + bias[dt][1]),
                          f2bf(acc[dt][pt][2] + bias[dt][2]),
                          f2bf(acc[dt][pt][3] + bias[dt][3]) };
            *(ushort4*)&As[pix * 136 + ch] = o;
        }
    __syncthreads();
    const int p = n0 >> 8, cbase = n0 & 255;
    ushort* outb = efp + (size_t)((b * PTS + p) * HW) * Cc;
    #pragma unroll
    for (int r = 0; r < 4; r++) {
        int pix = (t >> 4) + r * 16;
        int ch8 = (t & 15) * 8;
        if (pix0 + pix < HW)
            *(uint4*)&outb[(size_t)(pix0 + pix) * Cc + cbase + ch8] =
                *(const uint4*)&As[pix * 136 + ch8];
    }
}

// ---------------------------------------------------------------------------
// K2: heat[b][p][pix] = exp(sum_d w2[d]*relu(D[d][pix]+b1[d]) + b2)
// (round-4 proven structure)
// ---------------------------------------------------------------------------
__global__ __launch_bounds__(256)
void k_heat(const ushort* __restrict__ efp, const ushort* __restrict__ wb1,
            const float* __restrict__ b1, const float* __restrict__ w2,
            const float* __restrict__ b2, float* __restrict__ heat)
{
    __shared__ ushort As[256 * 72];
    __shared__ ushort Bs[64 * 72];
    __shared__ float red[4][64];
    const int t = threadIdx.x;
    const int wv = t >> 6, ln = t & 63;
    const int quad = ln >> 4, l16 = ln & 15;
    const int pix0 = blockIdx.x * 64;
    const int p = blockIdx.y;
    const int b = blockIdx.z;
    const ushort* efb_ = efp + (size_t)((b * PTS + p) * HW) * Cc;
    const ushort* w1p = wb1 + (size_t)p * Cc * Cc;

    f32x4 acc[4][4];
    #pragma unroll
    for (int i = 0; i < 4; i++)
        #pragma unroll
        for (int j = 0; j < 4; j++) acc[i][j] = (f32x4){0.f, 0.f, 0.f, 0.f};

    const int srow = t >> 3, scol = (t & 7) * 8;

    for (int k0 = 0; k0 < 256; k0 += 64) {
        #pragma unroll
        for (int r = 0; r < 8; r++) {
            int row = srow + r * 32;
            *(uint4*)&As[row * 72 + scol] =
                *(const uint4*)&w1p[(size_t)row * 256 + k0 + scol];
        }
        #pragma unroll
        for (int r = 0; r < 2; r++) {
            int row = srow + r * 32;
            int pq = pix0 + row; if (pq > HW - 1) pq = HW - 1;
            *(uint4*)&Bs[row * 72 + scol] =
                *(const uint4*)&efb_[(size_t)pq * Cc + k0 + scol];
        }
        __syncthreads();
        #pragma unroll
        for (int kk = 0; kk < 64; kk += 32) {
            bfrag af[4], bfr[4];
            #pragma unroll
            for (int dt = 0; dt < 4; dt++)
                af[dt] = *(const bfrag*)&As[(wv * 64 + dt * 16 + l16) * 72 + kk + quad * 8];
            #pragma unroll
            for (int pt = 0; pt < 4; pt++)
                bfr[pt] = *(const bfrag*)&Bs[(pt * 16 + l16) * 72 + kk + quad * 8];
            #pragma unroll
            for (int dt = 0; dt < 4; dt++)
                #pragma unroll
                for (int pt = 0; pt < 4; pt++)
                    acc[dt][pt] = __builtin_amdgcn_mfma_f32_16x16x32_bf16(
                        af[dt], bfr[pt], acc[dt][pt], 0, 0, 0);
        }
        __syncthreads();
    }

    const float* b1p = b1 + p * 256;
    const float* w2p = w2 + p * 256;
    float s[4] = {0.f, 0.f, 0.f, 0.f};
    #pragma unroll
    for (int dt = 0; dt < 4; dt++) {
        int chb = wv * 64 + dt * 16 + quad * 4;
        float bb[4], ww[4];
        #pragma unroll
        for (int r = 0; r < 4; r++) { bb[r] = b1p[chb + r]; ww[r] = w2p[chb + r]; }
        #pragma unroll
        for (int pt = 0; pt < 4; pt++)
            #pragma unroll
            for (int r = 0; r < 4; r++) {
                float h = acc[dt][pt][r] + bb[r];
                h = h > 0.f ? h : 0.f;
                s[pt] += ww[r] * h;
            }
    }
    #pragma unroll
    for (int pt = 0; pt < 4; pt++) {
        s[pt] += __shfl_xor(s[pt], 16);
        s[pt] += __shfl_xor(s[pt], 32);
    }
    if (ln < 16) {
        #pragma unroll
        for (int pt = 0; pt < 4; pt++) red[wv][pt * 16 + ln] = s[pt];
    }
    __syncthreads();
    if (t < 64) {
        float v = red[0][t] + red[1][t] + red[2][t] + red[3][t] + b2[p];
        int m = pix0 + t;
        if (m < HW) heat[(size_t)(b * PTS + p) * HW + m] = expf(v);
    }
}

// ---------------------------------------------------------------------------
// K3: deformable sampling (round-4 proven structure)
// ---------------------------------------------------------------------------
__global__ __launch_bounds__(256)
void k_sample(const ushort* __restrict__ efp, const float* __restrict__ heat,
              const float* __restrict__ offs, ushort* __restrict__ outs)
{
    __shared__ uint2 s_wo[32][20];
    const int t = threadIdx.x;
    const int bid = blockIdx.x;
    const int nx = (bid & 7) * 60 + (bid >> 3);
    if (nx >= 475) return;
    const int m0 = nx * 32;
    const int p = blockIdx.y;
    const int b = blockIdx.z;
    const float* heat_bp = heat + (size_t)(b * PTS + p) * HW;

    if (t < 32 * BINS) {
        int j = t / BINS, k = t % BINS;
        int hw = m0 + j;
        int hh = hw / Ww, ww = hw % Ww;
        int chy = (p * BINS + k) * 2;
        float oy = offs[((size_t)b * (PTS * BINS * 2) + chy)     * HW + hw];
        float ox = offs[((size_t)b * (PTS * BINS * 2) + chy + 1) * HW + hw];
        float ysf = (float)hh + oy;
        float xsf = (float)ww + ox;
        float y0 = floorf(ysf), x0 = floorf(xsf);
        #pragma unroll
        for (int dy = 0; dy < 2; dy++)
            #pragma unroll
            for (int dx = 0; dx < 2; dx++) {
                float yi = y0 + dy, xi = x0 + dx;
                float wgt = (1.f - fabsf(ysf - yi)) * (1.f - fabsf(xsf - xi));
                bool valid = (yi >= 0.f) && (yi <= (float)(Hh - 1)) &&
                             (xi >= 0.f) && (xi <= (float)(Ww - 1));
                int yc = (int)yi; yc = yc < 0 ? 0 : (yc > Hh - 1 ? Hh - 1 : yc);
                int xc = (int)xi; xc = xc < 0 ? 0 : (xc > Ww - 1 ? Ww - 1 : xc);
                int idx = yc * Ww + xc;
                float wh = valid ? wgt * heat_bp[idx] : 0.f;
                s_wo[j][k * 4 + dy * 2 + dx] =
                    make_uint2(__float_as_uint(wh), (unsigned)idx << 9);
            }
    }
    __syncthreads();
    if (t < 32) {
        float s = 0.f;
        #pragma unroll
        for (int u = 0; u < 20; u++) s += __uint_as_float(s_wo[t][u].x);
        float inv = 1.f / (s + EPS_DIV);
        #pragma unroll
        for (int u = 0; u < 20; u++)
            s_wo[t][u].x = __float_as_uint(__uint_as_float(s_wo[t][u].x) * inv);
    }
    __syncthreads();

    const int wv = t >> 6, ln = t & 63;
    const char* efbase = (const char*)(efp + (size_t)((b * PTS + p) * HW) * Cc)
                         + ln * 8;
    ushort* ob = outs + ((size_t)(b * HW + m0)) * (PTS * Cc) + p * Cc + ln * 4;
    #pragma unroll
    for (int i = 0; i < 8; i += 2) {
        const int j0 = wv * 8 + i, j1 = j0 + 1;
        float a0[4] = {0.f, 0.f, 0.f, 0.f};
        float a1[4] = {0.f, 0.f, 0.f, 0.f};
        #pragma unroll
        for (int u = 0; u < 20; u++) {
            uint2 wo0 = s_wo[j0][u];
            uint2 wo1 = s_wo[j1][u];
            uint2 v0 = *(const uint2*)(efbase + wo0.y);
            uint2 v1 = *(const uint2*)(efbase + wo1.y);
            float w0 = __uint_as_float(wo0.x);
            float w1 = __uint_as_float(wo1.x);
            a0[0] += w0 * bflo(v0.x); a0[1] += w0 * bfhi(v0.x);
            a0[2] += w0 * bflo(v0.y); a0[3] += w0 * bfhi(v0.y);
            a1[0] += w1 * bflo(v1.x); a1[1] += w1 * bfhi(v1.x);
            a1[2] += w1 * bflo(v1.y); a1[3] += w1 * bfhi(v1.y);
        }
        uint2 o0 = make_uint2(pack2(a0[0], a0[1]), pack2(a0[2], a0[3]));
        uint2 o1 = make_uint2(pack2(a1[0], a1[1]), pack2(a1[2], a1[3]));
        *(uint2*)(ob + (size_t)j0 * (PTS * Cc)) = o0;
        *(uint2*)(ob + (size_t)j1 * (PTS * Cc)) = o1;
    }
}

// ---------------------------------------------------------------------------
// K4: out[b][c][pix] (fp32) = merge_w @ outs + merge_b.  BN=64 (round-6).
// GN partials written contention-free to part2[b][g][tileX] — NO atomics.
// ---------------------------------------------------------------------------
__global__ __launch_bounds__(256)
void k_merge(const ushort* __restrict__ outs, const ushort* __restrict__ wbm,
             const float* __restrict__ mb, float* __restrict__ out,
             float* __restrict__ part2)
{
    __shared__ ushort As[64 * 72];      // [n][k]
    __shared__ ushort Bs[64 * 72];      // [pix][k]
    const int t = threadIdx.x;
    const int wv = t >> 6, ln = t & 63;
    const int quad = ln >> 4, l16 = ln & 15;
    const int pix0 = blockIdx.x * 64;
    const int n0 = blockIdx.y * 64;
    const int b = blockIdx.z;
    const ushort* ob = outs + (size_t)b * HW * (PTS * Cc);

    f32x4 acc[4];
    #pragma unroll
    for (int j = 0; j < 4; j++) acc[j] = (f32x4){0.f, 0.f, 0.f, 0.f};

    const int srow = t >> 3, scol = (t & 7) * 8;   // srow 0..31

    for (int k0 = 0; k0 < 512; k0 += 64) {
        #pragma unroll
        for (int r = 0; r < 2; r++) {
            int row = srow + r * 32;
            *(uint4*)&As[row * 72 + scol] =
                *(const uint4*)&wbm[(size_t)(n0 + row) * 512 + k0 + scol];
        }
        #pragma unroll
        for (int r = 0; r < 2; r++) {
            int row = srow + r * 32;
            int pq = pix0 + row; if (pq > HW - 1) pq = HW - 1;
            *(uint4*)&Bs[row * 72 + scol] =
                *(const uint4*)&ob[(size_t)pq * (PTS * Cc) + k0 + scol];
        }
        __syncthreads();
        #pragma unroll
        for (int kk = 0; kk < 64; kk += 32) {
            bfrag af = *(const bfrag*)&As[(wv * 16 + l16) * 72 + kk + quad * 8];
            #pragma unroll
            for (int pt = 0; pt < 4; pt++) {
                bfrag bfr = *(const bfrag*)&Bs[(pt * 16 + l16) * 72 + kk + quad * 8];
                acc[pt] = __builtin_amdgcn_mfma_f32_16x16x32_bf16(
                    af, bfr, acc[pt], 0, 0, 0);
            }
        }
        __syncthreads();
    }

    const int ch = n0 + wv * 16 + quad * 4;
    float bias[4];
    #pragma unroll
    for (int r = 0; r < 4; r++) bias[r] = mb[ch + r];

    float sacc = 0.f, qacc = 0.f;
    #pragma unroll
    for (int pt = 0; pt < 4; pt++) {
        int pix = pix0 + pt * 16 + l16;
        if (pix < HW) {
            #pragma unroll
            for (int r = 0; r < 4; r++) {
                float v = acc[pt][r] + bias[r];
                out[((size_t)b * Cc + ch + r) * HW + pix] = v;
                sacc += v; qacc += v * v;
            }
        }
    }
    #pragma unroll
    for (int off = 1; off <= 16; off <<= 1) {
        sacc += __shfl_xor(sacc, off);
        qacc += __shfl_xor(qacc, off);
    }
    if ((ln & 31) == 0) {
        int g = (n0 >> 3) + wv * 2 + (quad >> 1);
        size_t idx = ((size_t)(b * 32 + g) * NTILE + blockIdx.x) * 2;
        part2[idx + 0] = sacc;
        part2[idx + 1] = qacc;
    }
}

// ---------------------------------------------------------------------------
// K5: reduce per-tile GN partials -> mean/istd per (b,group).  64 blocks.
// ---------------------------------------------------------------------------
__global__ __launch_bounds__(256)
void k_gnfinal(const float* __restrict__ part2, float* __restrict__ statf)
{
    const int bg = blockIdx.x;           // 0..63
    const int t = threadIdx.x;
    float s = 0.f, q = 0.f;
    if (t < NTILE) {
        s = part2[((size_t)bg * NTILE + t) * 2 + 0];
        q = part2[((size_t)bg * NTILE + t) * 2 + 1];
    }
    #pragma unroll
    for (int off = 1; off <= 32; off <<= 1) {
        s += __shfl_xor(s, off);
        q += __shfl_xor(q, off);
    }
    __shared__ float rs[4], rq[4];
    int wid = t >> 6;
    if ((t & 63) == 0) { rs[wid] = s; rq[wid] = q; }
    __syncthreads();
    if (t == 0) {
        float S = rs[0] + rs[1] + rs[2] + rs[3];
        float Q = rq[0] + rq[1] + rq[2] + rq[3];
        const float n = 8.f * HW;
        float mean = S / n;
        float var  = Q / n - mean * mean;
        statf[bg * 2 + 0] = mean;
        statf[bg * 2 + 1] = rsqrtf(var + GN_EPS);
    }
}

// ---------------------------------------------------------------------------
// K6: apply GN scale/shift + ReLU in place
// ---------------------------------------------------------------------------
__global__ __launch_bounds__(256)
void k_gnapply(float* __restrict__ out, const float* __restrict__ statf,
               const float* __restrict__ gg, const float* __restrict__ gb)
{
    const int i4 = blockIdx.x * 256 + threadIdx.x;
    const int total4 = Bx * Cc * HW / 4;
    if (i4 >= total4) return;
    const int i = i4 * 4;
    const int CHW = Cc * HW;
    const int b = i / CHW;
    const int r = i - b * CHW;
    const int c = r / HW;
    const int g = c >> 3;
    float mean = statf[(b * 32 + g) * 2 + 0];
    float istd = statf[(b * 32 + g) * 2 + 1];
    float sc = istd * gg[c];
    float sh = gb[c] - mean * sc;
    float4 v = *(float4*)(out + i);
    v.x = fmaxf(v.x * sc + sh, 0.f);
    v.y = fmaxf(v.y * sc + sh, 0.f);
    v.z = fmaxf(v.z * sc + sh, 0.f);
    v.w = fmaxf(v.w * sc + sh, 0.f);
    *(float4*)(out + i) = v;
}

// ---------------------------------------------------------------------------
extern "C" void kernel_launch(void* const* d_in, const int* in_sizes, int n_in,
                              void* d_out, int out_size, void* d_ws, size_t ws_size,
                              hipStream_t stream)
{
    const float* x    = (const float*)d_in[0];
    const float* offs = (const float*)d_in[1];
    const float* efw  = (const float*)d_in[2];
    const float* efb  = (const float*)d_in[3];
    const float* w1   = (const float*)d_in[4];
    const float* b1   = (const float*)d_in[5];
    const float* w2   = (const float*)d_in[6];
    const float* b2   = (const float*)d_in[7];
    const float* mw   = (const float*)d_in[8];
    const float* mb   = (const float*)d_in[9];
    const float* gg   = (const float*)d_in[10];
    const float* gb   = (const float*)d_in[11];
    float* out = (float*)d_out;

    ushort* wb    = (ushort*)d_ws;
    ushort* wbe   = wb;                          // 131072
    ushort* wb1   = wb + 131072;
    ushort* wbm   = wb + 262144;
    ushort* efp   = wb + 393216;                 // B*P*HW*C bf16
    ushort* outsb = efp + (size_t)Bx * PTS * HW * Cc;
    float*  heat  = (float*)(outsb + (size_t)Bx * HW * PTS * Cc);
    float*  part2 = heat + (size_t)Bx * PTS * HW;   // 64*NTILE*2 floats
    float*  statf = part2 + (size_t)64 * NTILE * 2; // 128 floats

    dim3 blk(256);
    k_wconv  <<<dim3(384),              blk, 0, stream>>>(efw, w1, mw, wb);
    k_ef     <<<dim3(238, 4, Bx),       blk, 0, stream>>>(x, wbe, efb, efp);
    k_heat   <<<dim3(238, PTS, Bx),     blk, 0, stream>>>(efp, wb1, b1, w2, b2, heat);
    k_sample <<<dim3(480, PTS, Bx),     blk, 0, stream>>>(efp, heat, offs, outsb);
    k_merge  <<<dim3(NTILE, 4, Bx),     blk, 0, stream>>>(outsb, wbm, mb, out, part2);
    k_gnfinal<<<dim3(64),               blk, 0, stream>>>(part2, statf);
    k_gnapply<<<dim3(Bx * Cc * HW / 4 / 256), blk, 0, stream>>>(out, statf, gg, gb);
}

// Round 10
// 212.268 us; speedup vs baseline: 2.0661x; 1.0098x over previous
//
#include <hip/hip_runtime.h>

#define BINS 5
#define PTS  2
constexpr int Bx = 2, Cc = 256, Hh = 100, Ww = 152;
constexpr int HW = Hh * Ww;          // 15200
constexpr int NTILE = 238;           // merge pixel tiles (64 px each)
constexpr float EPS_DIV = 1e-6f;
constexpr float GN_EPS  = 1e-5f;

typedef __attribute__((ext_vector_type(8))) short bfrag;   // 8 bf16 (4 VGPRs)
typedef __attribute__((ext_vector_type(4))) float f32x4;   // MFMA C/D

__device__ __forceinline__ ushort f2bf(float f) {
    union { float f; unsigned u; } v; v.f = f;
    unsigned r = v.u + 0x7fffu + ((v.u >> 16) & 1u);
    return (ushort)(r >> 16);
}
__device__ __forceinline__ float bflo(unsigned u) {
    return __uint_as_float(u << 16);
}
__device__ __forceinline__ float bfhi(unsigned u) {
    return __uint_as_float(u & 0xffff0000u);
}
__device__ __forceinline__ unsigned pack2(float a, float b) {
    return (unsigned)f2bf(a) | ((unsigned)f2bf(b) << 16);
}

// ---------------------------------------------------------------------------
// K0: convert ef_w, hm1_w, merge_w to bf16 (each 131072 elems)
// ---------------------------------------------------------------------------
__global__ __launch_bounds__(256)
void k_wconv(const float* __restrict__ efw, const float* __restrict__ w1,
             const float* __restrict__ mw, ushort* __restrict__ wb)
{
    int gid = blockIdx.x * 256 + threadIdx.x;
    int e = gid * 4;
    int arr = e >> 17, off = e & 131071;
    const float* src = arr == 0 ? efw : (arr == 1 ? w1 : mw);
    float4 v = *(const float4*)(src + off);
    ushort4 o = { f2bf(v.x), f2bf(v.y), f2bf(v.z), f2bf(v.w) };
    *(ushort4*)(wb + e) = o;
}

// ---------------------------------------------------------------------------
// K0b: transpose+convert x[b][c][hw] fp32 -> xbt[b][hw][c] bf16 (proven R7)
// ---------------------------------------------------------------------------
__global__ __launch_bounds__(256)
void k_xt(const float* __restrict__ x, ushort* __restrict__ xbt)
{
    __shared__ float tile[32][33];
    const int t = threadIdx.x;
    const int hw0 = blockIdx.x * 32;
    const int c0 = blockIdx.y * 32;
    const int b = blockIdx.z;
    const float* xb = x + ((size_t)b * Cc + c0) * HW + hw0;
    const int tx = t & 31, ty = t >> 5;
    #pragma unroll
    for (int r = 0; r < 4; r++) {
        int c = ty + r * 8;
        tile[c][tx] = xb[(size_t)c * HW + tx];
    }
    __syncthreads();
    const int hwl = t >> 3, c4 = (t & 7) * 4;
    ushort4 o = { f2bf(tile[c4 + 0][hwl]), f2bf(tile[c4 + 1][hwl]),
                  f2bf(tile[c4 + 2][hwl]), f2bf(tile[c4 + 3][hwl]) };
    *(ushort4*)&xbt[((size_t)b * HW + hw0 + hwl) * Cc + c0 + c4] = o;
}

// ---------------------------------------------------------------------------
// K1: efp[b][p][pix][c] (bf16) = ef_w @ x + ef_b.  B staged from xbt (bf16,
// coalesced uint4) — no per-thread fp32 transpose repack.
// ---------------------------------------------------------------------------
__global__ __launch_bounds__(256)
void k_ef(const ushort* __restrict__ xbt, const ushort* __restrict__ wbe,
          const float* __restrict__ efb, ushort* __restrict__ efp)
{
    __shared__ ushort As[128 * 72];     // [n][k] pad 72
    __shared__ ushort Bs[64 * 72];      // [pix][k]
    const int t = threadIdx.x;
    const int wv = t >> 6, ln = t & 63;
    const int quad = ln >> 4, l16 = ln & 15;
    const int pix0 = blockIdx.x * 64;
    const int n0 = blockIdx.y * 128;
    const int b = blockIdx.z;
    const ushort* xb = xbt + (size_t)b * HW * Cc;

    f32x4 acc[2][4];
    #pragma unroll
    for (int i = 0; i < 2; i++)
        #pragma unroll
        for (int j = 0; j < 4; j++) acc[i][j] = (f32x4){0.f, 0.f, 0.f, 0.f};

    const int arow = t >> 3, acol = (t & 7) * 8;
    const int srow = t >> 3, scol = (t & 7) * 8;

    for (int k0 = 0; k0 < 256; k0 += 64) {
        #pragma unroll
        for (int r = 0; r < 4; r++) {
            int row = arow + r * 32;
            *(uint4*)&As[row * 72 + acol] =
                *(const uint4*)&wbe[(size_t)(n0 + row) * 256 + k0 + acol];
        }
        #pragma unroll
        for (int r = 0; r < 2; r++) {
            int row = srow + r * 32;
            int pq = pix0 + row; if (pq > HW - 1) pq = HW - 1;
            *(uint4*)&Bs[row * 72 + scol] =
                *(const uint4*)&xb[(size_t)pq * Cc + k0 + scol];
        }
        __syncthreads();
        #pragma unroll
        for (int kk = 0; kk < 64; kk += 32) {
            bfrag af[2], bfr[4];
            #pragma unroll
            for (int dt = 0; dt < 2; dt++)
                af[dt] = *(const bfrag*)&As[(wv * 32 + dt * 16 + l16) * 72 + kk + quad * 8];
            #pragma unroll
            for (int pt = 0; pt < 4; pt++)
                bfr[pt] = *(const bfrag*)&Bs[(pt * 16 + l16) * 72 + kk + quad * 8];
            #pragma unroll
            for (int dt = 0; dt < 2; dt++)
                #pragma unroll
                for (int pt = 0; pt < 4; pt++)
                    acc[dt][pt] = __builtin_amdgcn_mfma_f32_16x16x32_bf16(
                        af[dt], bfr[pt], acc[dt][pt], 0, 0, 0);
        }
        __syncthreads();
    }

    float bias[2][4];
    #pragma unroll
    for (int dt = 0; dt < 2; dt++)
        #pragma unroll
        for (int r = 0; r < 4; r++)
            bias[dt][r] = efb[n0 + wv * 32 + dt * 16 + quad * 4 + r];
    #pragma unroll
    for (int dt = 0; dt < 2; dt++)
        #pragma unroll
        for (int pt = 0; pt < 4; pt++) {
            int pix = pt * 16 + l16;
            int ch = wv * 32 + dt * 16 + quad * 4;
            ushort4 o = { f2bf(acc[dt][pt][0] + bias[dt][0]),
                          f2bf(acc[dt][pt][1] + bias[dt][1]),
                          f2bf(acc[dt][pt][2] + bias[dt][2]),
                          f2bf(acc[dt][pt][3] + bias[dt][3]) };
            *(ushort4*)&As[pix * 136 + ch] = o;
        }
    __syncthreads();
    const int p = n0 >> 8, cbase = n0 & 255;
    ushort* outb = efp + (size_t)((b * PTS + p) * HW) * Cc;
    #pragma unroll
    for (int r = 0; r < 4; r++) {
        int pix = (t >> 4) + r * 16;
        int ch8 = (t & 15) * 8;
        if (pix0 + pix < HW)
            *(uint4*)&outb[(size_t)(pix0 + pix) * Cc + cbase + ch8] =
                *(const uint4*)&As[pix * 136 + ch8];
    }
}

// ---------------------------------------------------------------------------
// K2: heat[b][p][pix] = exp(sum_d w2[d]*relu(D[d][pix]+b1[d]) + b2)
// (round-4 proven structure)
// ---------------------------------------------------------------------------
__global__ __launch_bounds__(256)
void k_heat(const ushort* __restrict__ efp, const ushort* __restrict__ wb1,
            const float* __restrict__ b1, const float* __restrict__ w2,
            const float* __restrict__ b2, float* __restrict__ heat)
{
    __shared__ ushort As[256 * 72];
    __shared__ ushort Bs[64 * 72];
    __shared__ float red[4][64];
    const int t = threadIdx.x;
    const int wv = t >> 6, ln = t & 63;
    const int quad = ln >> 4, l16 = ln & 15;
    const int pix0 = blockIdx.x * 64;
    const int p = blockIdx.y;
    const int b = blockIdx.z;
    const ushort* efb_ = efp + (size_t)((b * PTS + p) * HW) * Cc;
    const ushort* w1p = wb1 + (size_t)p * Cc * Cc;

    f32x4 acc[4][4];
    #pragma unroll
    for (int i = 0; i < 4; i++)
        #pragma unroll
        for (int j = 0; j < 4; j++) acc[i][j] = (f32x4){0.f, 0.f, 0.f, 0.f};

    const int srow = t >> 3, scol = (t & 7) * 8;

    for (int k0 = 0; k0 < 256; k0 += 64) {
        #pragma unroll
        for (int r = 0; r < 8; r++) {
            int row = srow + r * 32;
            *(uint4*)&As[row * 72 + scol] =
                *(const uint4*)&w1p[(size_t)row * 256 + k0 + scol];
        }
        #pragma unroll
        for (int r = 0; r < 2; r++) {
            int row = srow + r * 32;
            int pq = pix0 + row; if (pq > HW - 1) pq = HW - 1;
            *(uint4*)&Bs[row * 72 + scol] =
                *(const uint4*)&efb_[(size_t)pq * Cc + k0 + scol];
        }
        __syncthreads();
        #pragma unroll
        for (int kk = 0; kk < 64; kk += 32) {
            bfrag af[4], bfr[4];
            #pragma unroll
            for (int dt = 0; dt < 4; dt++)
                af[dt] = *(const bfrag*)&As[(wv * 64 + dt * 16 + l16) * 72 + kk + quad * 8];
            #pragma unroll
            for (int pt = 0; pt < 4; pt++)
                bfr[pt] = *(const bfrag*)&Bs[(pt * 16 + l16) * 72 + kk + quad * 8];
            #pragma unroll
            for (int dt = 0; dt < 4; dt++)
                #pragma unroll
                for (int pt = 0; pt < 4; pt++)
                    acc[dt][pt] = __builtin_amdgcn_mfma_f32_16x16x32_bf16(
                        af[dt], bfr[pt], acc[dt][pt], 0, 0, 0);
        }
        __syncthreads();
    }

    const float* b1p = b1 + p * 256;
    const float* w2p = w2 + p * 256;
    float s[4] = {0.f, 0.f, 0.f, 0.f};
    #pragma unroll
    for (int dt = 0; dt < 4; dt++) {
        int chb = wv * 64 + dt * 16 + quad * 4;
        float bb[4], ww[4];
        #pragma unroll
        for (int r = 0; r < 4; r++) { bb[r] = b1p[chb + r]; ww[r] = w2p[chb + r]; }
        #pragma unroll
        for (int pt = 0; pt < 4; pt++)
            #pragma unroll
            for (int r = 0; r < 4; r++) {
                float h = acc[dt][pt][r] + bb[r];
                h = h > 0.f ? h : 0.f;
                s[pt] += ww[r] * h;
            }
    }
    #pragma unroll
    for (int pt = 0; pt < 4; pt++) {
        s[pt] += __shfl_xor(s[pt], 16);
        s[pt] += __shfl_xor(s[pt], 32);
    }
    if (ln < 16) {
        #pragma unroll
        for (int pt = 0; pt < 4; pt++) red[wv][pt * 16 + ln] = s[pt];
    }
    __syncthreads();
    if (t < 64) {
        float v = red[0][t] + red[1][t] + red[2][t] + red[3][t] + b2[p];
        int m = pix0 + t;
        if (m < HW) heat[(size_t)(b * PTS + p) * HW + m] = expf(v);
    }
}

// ---------------------------------------------------------------------------
// K3: deformable sampling.  Lane-half = pixel, lane&31 = 8-channel group:
// uint4 gathers (32 lanes x 16B = 512B/pixel), half the load instructions.
// ---------------------------------------------------------------------------
__global__ __launch_bounds__(256)
void k_sample(const ushort* __restrict__ efp, const float* __restrict__ heat,
              const float* __restrict__ offs, ushort* __restrict__ outs)
{
    __shared__ uint2 s_wo[32][20];
    const int t = threadIdx.x;
    const int bid = blockIdx.x;
    const int nx = (bid & 7) * 60 + (bid >> 3);
    if (nx >= 475) return;
    const int m0 = nx * 32;
    const int p = blockIdx.y;
    const int b = blockIdx.z;
    const float* heat_bp = heat + (size_t)(b * PTS + p) * HW;

    if (t < 32 * BINS) {
        int j = t / BINS, k = t % BINS;
        int hw = m0 + j;
        int hh = hw / Ww, ww = hw % Ww;
        int chy = (p * BINS + k) * 2;
        float oy = offs[((size_t)b * (PTS * BINS * 2) + chy)     * HW + hw];
        float ox = offs[((size_t)b * (PTS * BINS * 2) + chy + 1) * HW + hw];
        float ysf = (float)hh + oy;
        float xsf = (float)ww + ox;
        float y0 = floorf(ysf), x0 = floorf(xsf);
        #pragma unroll
        for (int dy = 0; dy < 2; dy++)
            #pragma unroll
            for (int dx = 0; dx < 2; dx++) {
                float yi = y0 + dy, xi = x0 + dx;
                float wgt = (1.f - fabsf(ysf - yi)) * (1.f - fabsf(xsf - xi));
                bool valid = (yi >= 0.f) && (yi <= (float)(Hh - 1)) &&
                             (xi >= 0.f) && (xi <= (float)(Ww - 1));
                int yc = (int)yi; yc = yc < 0 ? 0 : (yc > Hh - 1 ? Hh - 1 : yc);
                int xc = (int)xi; xc = xc < 0 ? 0 : (xc > Ww - 1 ? Ww - 1 : xc);
                int idx = yc * Ww + xc;
                float wh = valid ? wgt * heat_bp[idx] : 0.f;
                s_wo[j][k * 4 + dy * 2 + dx] =
                    make_uint2(__float_as_uint(wh), (unsigned)idx << 9);
            }
    }
    __syncthreads();
    if (t < 32) {
        float s = 0.f;
        #pragma unroll
        for (int u = 0; u < 20; u++) s += __uint_as_float(s_wo[t][u].x);
        float inv = 1.f / (s + EPS_DIV);
        #pragma unroll
        for (int u = 0; u < 20; u++)
            s_wo[t][u].x = __float_as_uint(__uint_as_float(s_wo[t][u].x) * inv);
    }
    __syncthreads();

    // phase 2: lane-half = pixel, lane&31 = 8-channel group
    const int wv = t >> 6, ln = t & 63;
    const int half = ln >> 5, c8 = ln & 31;
    const char* efbase = (const char*)(efp + (size_t)((b * PTS + p) * HW) * Cc)
                         + c8 * 16;
    ushort* ob = outs + ((size_t)(b * HW + m0)) * (PTS * Cc) + p * Cc + c8 * 8;
    #pragma unroll
    for (int i = 0; i < 8; i += 2) {
        const int j = wv * 8 + i + half;
        float a[8] = {0.f, 0.f, 0.f, 0.f, 0.f, 0.f, 0.f, 0.f};
        #pragma unroll
        for (int u = 0; u < 20; u++) {
            uint2 wo = s_wo[j][u];
            uint4 v = *(const uint4*)(efbase + wo.y);
            float w = __uint_as_float(wo.x);
            a[0] += w * bflo(v.x); a[1] += w * bfhi(v.x);
            a[2] += w * bflo(v.y); a[3] += w * bfhi(v.y);
            a[4] += w * bflo(v.z); a[5] += w * bfhi(v.z);
            a[6] += w * bflo(v.w); a[7] += w * bfhi(v.w);
        }
        uint4 o = { pack2(a[0], a[1]), pack2(a[2], a[3]),
                    pack2(a[4], a[5]), pack2(a[6], a[7]) };
        *(uint4*)(ob + (size_t)j * (PTS * Cc)) = o;
    }
}

// ---------------------------------------------------------------------------
// K4: mgb[b][c][pix] (bf16) = merge_w @ outs + merge_b.  BN=64, no atomics;
// GN partials to part2[b][g][tileX].
// ---------------------------------------------------------------------------
__global__ __launch_bounds__(256)
void k_merge(const ushort* __restrict__ outs, const ushort* __restrict__ wbm,
             const float* __restrict__ mb, ushort* __restrict__ mgb,
             float* __restrict__ part2)
{
    __shared__ ushort As[64 * 72];      // [n][k]
    __shared__ ushort Bs[64 * 72];      // [pix][k]
    const int t = threadIdx.x;
    const int wv = t >> 6, ln = t & 63;
    const int quad = ln >> 4, l16 = ln & 15;
    const int pix0 = blockIdx.x * 64;
    const int n0 = blockIdx.y * 64;
    const int b = blockIdx.z;
    const ushort* ob = outs + (size_t)b * HW * (PTS * Cc);

    f32x4 acc[4];
    #pragma unroll
    for (int j = 0; j < 4; j++) acc[j] = (f32x4){0.f, 0.f, 0.f, 0.f};

    const int srow = t >> 3, scol = (t & 7) * 8;   // srow 0..31

    for (int k0 = 0; k0 < 512; k0 += 64) {
        #pragma unroll
        for (int r = 0; r < 2; r++) {
            int row = srow + r * 32;
            *(uint4*)&As[row * 72 + scol] =
                *(const uint4*)&wbm[(size_t)(n0 + row) * 512 + k0 + scol];
        }
        #pragma unroll
        for (int r = 0; r < 2; r++) {
            int row = srow + r * 32;
            int pq = pix0 + row; if (pq > HW - 1) pq = HW - 1;
            *(uint4*)&Bs[row * 72 + scol] =
                *(const uint4*)&ob[(size_t)pq * (PTS * Cc) + k0 + scol];
        }
        __syncthreads();
        #pragma unroll
        for (int kk = 0; kk < 64; kk += 32) {
            bfrag af = *(const bfrag*)&As[(wv * 16 + l16) * 72 + kk + quad * 8];
            #pragma unroll
            for (int pt = 0; pt < 4; pt++) {
                bfrag bfr = *(const bfrag*)&Bs[(pt * 16 + l16) * 72 + kk + quad * 8];
                acc[pt] = __builtin_amdgcn_mfma_f32_16x16x32_bf16(
                    af, bfr, acc[pt], 0, 0, 0);
            }
        }
        __syncthreads();
    }

    const int ch = n0 + wv * 16 + quad * 4;
    float bias[4];
    #pragma unroll
    for (int r = 0; r < 4; r++) bias[r] = mb[ch + r];

    float sacc = 0.f, qacc = 0.f;
    #pragma unroll
    for (int pt = 0; pt < 4; pt++) {
        int pix = pix0 + pt * 16 + l16;
        if (pix < HW) {
            #pragma unroll
            for (int r = 0; r < 4; r++) {
                float v = acc[pt][r] + bias[r];
                mgb[((size_t)b * Cc + ch + r) * HW + pix] = f2bf(v);
                sacc += v; qacc += v * v;
            }
        }
    }
    #pragma unroll
    for (int off = 1; off <= 16; off <<= 1) {
        sacc += __shfl_xor(sacc, off);
        qacc += __shfl_xor(qacc, off);
    }
    if ((ln & 31) == 0) {
        int g = (n0 >> 3) + wv * 2 + (quad >> 1);
        size_t idx = ((size_t)(b * 32 + g) * NTILE + blockIdx.x) * 2;
        part2[idx + 0] = sacc;
        part2[idx + 1] = qacc;
    }
}

// ---------------------------------------------------------------------------
// K5: reduce per-tile GN partials -> mean/istd per (b,group).  64 blocks.
// ---------------------------------------------------------------------------
__global__ __launch_bounds__(256)
void k_gnfinal(const float* __restrict__ part2, float* __restrict__ statf)
{
    const int bg = blockIdx.x;           // 0..63
    const int t = threadIdx.x;
    float s = 0.f, q = 0.f;
    if (t < NTILE) {
        s = part2[((size_t)bg * NTILE + t) * 2 + 0];
        q = part2[((size_t)bg * NTILE + t) * 2 + 1];
    }
    #pragma unroll
    for (int off = 1; off <= 32; off <<= 1) {
        s += __shfl_xor(s, off);
        q += __shfl_xor(q, off);
    }
    __shared__ float rs[4], rq[4];
    int wid = t >> 6;
    if ((t & 63) == 0) { rs[wid] = s; rq[wid] = q; }
    __syncthreads();
    if (t == 0) {
        float S = rs[0] + rs[1] + rs[2] + rs[3];
        float Q = rq[0] + rq[1] + rq[2] + rq[3];
        const float n = 8.f * HW;
        float mean = S / n;
        float var  = Q / n - mean * mean;
        statf[bg * 2 + 0] = mean;
        statf[bg * 2 + 1] = rsqrtf(var + GN_EPS);
    }
}

// ---------------------------------------------------------------------------
// K6: apply GN scale/shift + ReLU: read bf16 mgb, write fp32 out
// ---------------------------------------------------------------------------
__global__ __launch_bounds__(256)
void k_gnapply(const ushort* __restrict__ mgb, const float* __restrict__ statf,
               const float* __restrict__ gg, const float* __restrict__ gb,
               float* __restrict__ out)
{
    const int i8 = blockIdx.x * 256 + threadIdx.x;   // 3800 blocks exact
    const int i = i8 * 8;
    const int CHW = Cc * HW;
    const int b = i / CHW;
    const int r = i - b * CHW;
    const int c = r / HW;
    const int g = c >> 3;
    float mean = statf[(b * 32 + g) * 2 + 0];
    float istd = statf[(b * 32 + g) * 2 + 1];
    float sc = istd * gg[c];
    float sh = gb[c] - mean * sc;
    uint4 v = *(const uint4*)(mgb + i);
    float4 o0, o1;
    o0.x = fmaxf(bflo(v.x) * sc + sh, 0.f);
    o0.y = fmaxf(bfhi(v.x) * sc + sh, 0.f);
    o0.z = fmaxf(bflo(v.y) * sc + sh, 0.f);
    o0.w = fmaxf(bfhi(v.y) * sc + sh, 0.f);
    o1.x = fmaxf(bflo(v.z) * sc + sh, 0.f);
    o1.y = fmaxf(bfhi(v.z) * sc + sh, 0.f);
    o1.z = fmaxf(bflo(v.w) * sc + sh, 0.f);
    o1.w = fmaxf(bfhi(v.w) * sc + sh, 0.f);
    *(float4*)(out + i)     = o0;
    *(float4*)(out + i + 4) = o1;
}

// ---------------------------------------------------------------------------
extern "C" void kernel_launch(void* const* d_in, const int* in_sizes, int n_in,
                              void* d_out, int out_size, void* d_ws, size_t ws_size,
                              hipStream_t stream)
{
    const float* x    = (const float*)d_in[0];
    const float* offs = (const float*)d_in[1];
    const float* efw  = (const float*)d_in[2];
    const float* efb  = (const float*)d_in[3];
    const float* w1   = (const float*)d_in[4];
    const float* b1   = (const float*)d_in[5];
    const float* w2   = (const float*)d_in[6];
    const float* b2   = (const float*)d_in[7];
    const float* mw   = (const float*)d_in[8];
    const float* mb   = (const float*)d_in[9];
    const float* gg   = (const float*)d_in[10];
    const float* gb   = (const float*)d_in[11];
    float* out = (float*)d_out;

    ushort* wb    = (ushort*)d_ws;
    ushort* wbe   = wb;                          // 131072
    ushort* wb1   = wb + 131072;
    ushort* wbm   = wb + 262144;
    ushort* efp   = wb + 393216;                        // B*P*HW*C bf16
    ushort* outsb = efp + (size_t)Bx * PTS * HW * Cc;   // B*HW*P*C bf16
    ushort* xbt   = outsb + (size_t)Bx * HW * PTS * Cc; // B*HW*C bf16
    ushort* mgb   = xbt + (size_t)Bx * HW * Cc;         // B*C*HW bf16
    float*  heat  = (float*)(mgb + (size_t)Bx * Cc * HW);
    float*  part2 = heat + (size_t)Bx * PTS * HW;       // 64*NTILE*2 floats
    float*  statf = part2 + (size_t)64 * NTILE * 2;     // 128 floats

    dim3 blk(256);
    k_wconv  <<<dim3(384),              blk, 0, stream>>>(efw, w1, mw, wb);
    k_xt     <<<dim3(475, 8, Bx),       blk, 0, stream>>>(x, xbt);
    k_ef     <<<dim3(238, 4, Bx),       blk, 0, stream>>>(xbt, wbe, efb, efp);
    k_heat   <<<dim3(238, PTS, Bx),     blk, 0, stream>>>(efp, wb1, b1, w2, b2, heat);
    k_sample <<<dim3(480, PTS, Bx),     blk, 0, stream>>>(efp, heat, offs, outsb);
    k_merge  <<<dim3(NTILE, 4, Bx),     blk, 0, stream>>>(outsb, wbm, mb, mgb, part2);
    k_gnfinal<<<dim3(64),               blk, 0, stream>>>(part2, statf);
    k_gnapply<<<dim3(Bx * Cc * HW / 8 / 256), blk, 0, stream>>>(mgb, statf, gg, gb, out);
}